// Round 12
// baseline (686.674 us; speedup 1.0000x reference)
//
#include <hip/hip_runtime.h>
#include <math.h>

#define N_NODES 50000
#define N_EDGES 800000

typedef __attribute__((ext_vector_type(8))) short bf16x8;
typedef __attribute__((ext_vector_type(4))) short bf16x4;
typedef __attribute__((ext_vector_type(2))) short shortx2;
typedef __attribute__((ext_vector_type(4))) float f32x4;

__device__ __forceinline__ float silu_f(float x) {
    float d = 1.0f + __expf(-x);
    return x * __builtin_amdgcn_rcpf(d);
}

__device__ __forceinline__ unsigned short f2bf(float x) {
    union { float f; unsigned u; } v; v.f = x;
    unsigned r = v.u + 0x7FFFu + ((v.u >> 16) & 1u);
    return (unsigned short)(r >> 16);
}

__device__ __forceinline__ void atomic_pk_add_bf16(short* addr, shortx2 v) {
    typedef shortx2 __attribute__((address_space(1)))* gp1;
    __builtin_amdgcn_global_atomic_fadd_v2bf16((gp1)(unsigned long long)addr, v);
}

// ---------------------------------------------------------------------------
// K1: fused h f32->bf16 + CSR degree count (blocks 0..3124) and
//     H = A + A^H, X0 = H - iI (blocks 3125..3132).
// ---------------------------------------------------------------------------
__global__ __launch_bounds__(256) void prep_kernel(const float* __restrict__ h,
                                                   short* __restrict__ hbf,
                                                   const int* __restrict__ ei,
                                                   int* __restrict__ cnt,
                                                   const float* __restrict__ A_real,
                                                   const float* __restrict__ A_imag,
                                                   float* __restrict__ H,
                                                   float* __restrict__ X) {
    const int bid = blockIdx.x;
    const int t = threadIdx.x;
    if (bid < 3125) {
        int i = bid * 256 + t;
        const float4* h4 = (const float4*)h;
        float4 v0 = h4[i * 2], v1 = h4[i * 2 + 1];
        bf16x8 b;
        b[0] = (short)f2bf(v0.x); b[1] = (short)f2bf(v0.y);
        b[2] = (short)f2bf(v0.z); b[3] = (short)f2bf(v0.w);
        b[4] = (short)f2bf(v1.x); b[5] = (short)f2bf(v1.y);
        b[6] = (short)f2bf(v1.z); b[7] = (short)f2bf(v1.w);
        ((bf16x8*)hbf)[i] = b;
        atomicAdd(&cnt[ei[i]], 1);
    } else {
        int p = bid - 3125;          // 0..7
        int L = p >> 2, q4 = p & 3;
        const float* ar = A_real + L * 16384;
        const float* ai = A_imag + L * 16384;
        float* hre = H + L * 32768;
        float* him = hre + 16384;
        float* xre = X + L * 32768;
        float* xim = xre + 16384;
        for (int m = 0; m < 16; ++m) {
            int idx = q4 * 4096 + t + 256 * m;
            int i = idx >> 7, j = idx & 127;
            float hr = ar[idx] + ar[j * 128 + i];
            float hi = ai[idx] - ai[j * 128 + i];
            hre[idx] = hr;
            him[idx] = hi;
            xre[idx] = hr;
            xim[idx] = hi - (i == j ? 1.0f : 0.0f);
        }
    }
}

// ---------------------------------------------------------------------------
// NS bodies (1024 threads, 32 blocks: 16 per layer, 8 rows each)
// ---------------------------------------------------------------------------
__device__ __forceinline__ void ns_t_body(int blk, int t,
                                          const float* __restrict__ H,
                                          const float* __restrict__ X,
                                          float* __restrict__ T) {
    const int L = blk >> 4;
    const int i = (blk & 15) * 8 + (t >> 7);
    const int j = t & 127;
    const float* hre = H + L * 32768;
    const float* him = hre + 16384;
    const float* xre = X + L * 32768;
    const float* xim = xre + 16384;
    float accr = 0.f, acci = 0.f;
    #pragma unroll 4
    for (int k = 0; k < 128; ++k) {
        float hr = hre[i * 128 + k], hi = him[i * 128 + k];
        float xr = xre[k * 128 + j], xi = xim[k * 128 + j];
        accr += hr * xr - hi * xi;
        acci += hr * xi + hi * xr;
    }
    T[L * 32768 + i * 128 + j]          = accr - xim[i * 128 + j];
    T[L * 32768 + 16384 + i * 128 + j]  = acci + xre[i * 128 + j];
}

__device__ __forceinline__ void ns_x_body(int blk, int t,
                                          const float* __restrict__ X,
                                          const float* __restrict__ T,
                                          float* __restrict__ Xout) {
    const int L = blk >> 4;
    const int i = (blk & 15) * 8 + (t >> 7);
    const int j = t & 127;
    const float* xre = X + L * 32768;
    const float* xim = xre + 16384;
    const float* tre = T + L * 32768;
    const float* tim = tre + 16384;
    float accr = 0.f, acci = 0.f;
    #pragma unroll 4
    for (int k = 0; k < 128; ++k) {
        float xr = xre[i * 128 + k], xi = xim[i * 128 + k];
        float tr = tre[k * 128 + j], ti = tim[k * 128 + j];
        accr += xr * tr - xi * ti;
        acci += xr * ti + xi * tr;
    }
    Xout[L * 32768 + i * 128 + j]          = 2.0f * xre[i * 128 + j] - accr;
    Xout[L * 32768 + 16384 + i * 128 + j]  = 2.0f * xim[i * 128 + j] - acci;
}

// ---------------------------------------------------------------------------
// K2: blocks 0..31 ns_t(iter1), block 32: CSR exclusive scan.
// ---------------------------------------------------------------------------
__global__ __launch_bounds__(1024) void nst_scan_kernel(const float* __restrict__ H,
                                                        const float* __restrict__ X,
                                                        float* __restrict__ T,
                                                        const int* __restrict__ cnt,
                                                        int* __restrict__ cursor) {
    const int bid = blockIdx.x;
    const int t = threadIdx.x;
    if (bid < 32) { ns_t_body(bid, t, H, X, T); return; }
    __shared__ int sA[1024];
    __shared__ int sB[1024];
    const int CH = 49;
    int s = 0;
    #pragma unroll 4
    for (int i = 0; i < CH; ++i) {
        int idx = t * CH + i;
        if (idx < N_NODES) s += cnt[idx];
    }
    sA[t] = s;
    __syncthreads();
    int* src = sA;
    int* dst = sB;
    for (int off = 1; off < 1024; off <<= 1) {
        int v = src[t];
        if (t >= off) v += src[t - off];
        dst[t] = v;
        __syncthreads();
        int* tmp = src; src = dst; dst = tmp;
    }
    int run = (t == 0) ? 0 : src[t - 1];
    for (int i = 0; i < CH; ++i) {
        int idx = t * CH + i;
        if (idx < N_NODES) {
            cursor[idx] = run;
            run += cnt[idx];
        }
    }
}

// ---------------------------------------------------------------------------
// K3: blocks 0..781 CSR fill, blocks 782..813 ns_x(iter1).
// ---------------------------------------------------------------------------
__global__ __launch_bounds__(1024) void fill_nsx_kernel(const int* __restrict__ ei,
                                                        int* __restrict__ cursor,
                                                        int* __restrict__ elist,
                                                        const float* __restrict__ X,
                                                        const float* __restrict__ T,
                                                        float* __restrict__ Xout) {
    const int bid = blockIdx.x;
    const int t = threadIdx.x;
    if (bid < 782) {
        int e = bid * 1024 + t;
        if (e < N_EDGES) {
            int slot = atomicAdd(&cursor[ei[e]], 1);
            elist[slot] = e;
        }
        return;
    }
    ns_x_body(bid - 782, t, X, T, Xout);
}

__global__ __launch_bounds__(1024) void ns_t_kernel(const float* __restrict__ H,
                                                    const float* __restrict__ X,
                                                    float* __restrict__ T) {
    ns_t_body(blockIdx.x, threadIdx.x, H, X, T);
}

__global__ __launch_bounds__(1024) void ns_x_kernel(const float* __restrict__ X,
                                                    const float* __restrict__ T,
                                                    float* __restrict__ Xout) {
    ns_x_body(blockIdx.x, threadIdx.x, X, T, Xout);
}

// ---------------------------------------------------------------------------
// Q = I - 2i*X ; G^{x7} butterflies on row index; CNOT row gather.
// ---------------------------------------------------------------------------
__global__ __launch_bounds__(1024) void gateperm_kernel(const float* __restrict__ X,
                                                        const float* __restrict__ coeffs,
                                                        float* __restrict__ Y) {
    __shared__ float Mre[128 * 129];
    __shared__ float Mim[128 * 129];
    const int L = blockIdx.x;
    const int t = threadIdx.x;
    const float* xre = X + L * 32768;
    const float* xim = xre + 16384;

    for (int q = 0; q < 16; ++q) {
        int idx = t + 1024 * q;
        int i = idx >> 7, j = idx & 127;
        Mre[i * 129 + j] = (i == j ? 1.0f : 0.0f) + 2.0f * xim[idx];
        Mim[i * 129 + j] = -2.0f * xre[idx];
    }
    __syncthreads();

    const float tx = coeffs[2 * L + 0] * 0.5f;
    const float ty = coeffs[2 * L + 1] * 0.5f;
    const float cx = cosf(tx), sx = sinf(tx), cy = cosf(ty), sy = sinf(ty);
    const float G00r = cx * cy, G00i = sx * sy;
    const float G01r = -cx * sy, G01i = -sx * cy;
    const float G10r = cx * sy, G10i = -sx * cy;
    const float G11r = cx * cy, G11i = -sx * sy;

    for (int st = 0; st < 7; ++st) {
        int b = 1 << st;
        #pragma unroll
        for (int p = 0; p < 8; ++p) {
            int pid = t + 1024 * p;
            int col = pid & 127, ph = pid >> 7;
            int i0 = ((ph >> st) << (st + 1)) | (ph & (b - 1));
            int i1 = i0 | b;
            float v0r = Mre[i0 * 129 + col], v0i = Mim[i0 * 129 + col];
            float v1r = Mre[i1 * 129 + col], v1i = Mim[i1 * 129 + col];
            Mre[i0 * 129 + col] = G00r * v0r - G00i * v0i + G01r * v1r - G01i * v1i;
            Mim[i0 * 129 + col] = G00r * v0i + G00i * v0r + G01r * v1i + G01i * v1r;
            Mre[i1 * 129 + col] = G10r * v0r - G10i * v0i + G11r * v1r - G11i * v1i;
            Mim[i1 * 129 + col] = G10r * v0i + G10i * v0r + G11r * v1i + G11i * v1r;
        }
        __syncthreads();
    }

    const int cs[7] = {6, 5, 4, 3, 2, 1, 0};
    const int ts[7] = {0, 6, 5, 4, 3, 2, 1};
    float* yre = Y + L * 32768;
    float* yim = yre + 16384;
    for (int q = 0; q < 16; ++q) {
        int idx = t + 1024 * q;
        int ii_ = idx >> 7, col = idx & 127;
        int s = ii_;
        #pragma unroll
        for (int m = 0; m < 7; ++m) {
            int cbit = 1 << (6 - cs[m]);
            int tbit = 1 << (6 - ts[m]);
            if (s & cbit) s ^= tbit;
        }
        yre[idx] = Mre[s * 129 + col];
        yim[idx] = Mim[s * 129 + col];
    }
}

__global__ __launch_bounds__(512) void combine1_kernel(const float* __restrict__ Y,
                                                       float* __restrict__ ReM) {
    __shared__ float q1r[16384];
    __shared__ float q1i[16384];
    const int t = threadIdx.x;
    const float* q1re = Y;
    const float* q1im = Y + 16384;
    const float* q2re = Y + 32768;
    const float* q2im = Y + 49152;
    for (int q = 0; q < 32; ++q) {
        q1r[t + 512 * q] = q1re[t + 512 * q];
        q1i[t + 512 * q] = q1im[t + 512 * q];
    }
    __syncthreads();
    int i = blockIdx.x * 4 + (t >> 7);
    int j = t & 127;
    float acc = 0.f;
    for (int k = 0; k < 128; ++k) {
        acc += q2re[i * 128 + k] * q1r[k * 128 + j] - q2im[i * 128 + k] * q1i[k * 128 + j];
    }
    ReM[i * 128 + j] = acc;
}

__global__ __launch_bounds__(512) void combine2_kernel(const float* __restrict__ ReM,
                                                       const float* __restrict__ W_dec,
                                                       short* __restrict__ Dt) {
    __shared__ float ml[16384];
    __shared__ float wl[16384];
    const int t = threadIdx.x;
    for (int q = 0; q < 32; ++q) {
        ml[t + 512 * q] = ReM[t + 512 * q];
        wl[t + 512 * q] = W_dec[t + 512 * q];
    }
    __syncthreads();
    int k = blockIdx.x * 4 + (t >> 7);
    int j = t & 127;
    float acc = 0.f;
    for (int i = 0; i < 128; ++i) {
        acc += ml[i * 128 + k] * wl[i * 128 + j];
    }
    Dt[j * 128 + k] = (short)f2bf(acc);
}

// ---------------------------------------------------------------------------
// Edge MLP, 32-edge tiles (2 sub-tiles share each weight B fragment -> LDS
// B-traffic per edge halved, MFMA:B-read = 2:1). 8 waves/block, 2 waves/EU
// (256-VGPR budget, no spill). Frag-linear weights (0-conflict), stride-68
// c1 scratch, CSR contiguous ranges, carried per-sub run aggregation.
// ---------------------------------------------------------------------------
__global__ __launch_bounds__(512)
__attribute__((amdgpu_waves_per_eu(2, 2)))
void edge_kernel(const short* __restrict__ hbf,
                 const int* __restrict__ ei,
                 const int* __restrict__ elist,
                 const float* __restrict__ W_e1,
                 const float* __restrict__ b_e1,
                 const float* __restrict__ W_e2,
                 const float* __restrict__ b_e2,
                 float* __restrict__ ef_out,
                 short* __restrict__ agg_bf) {
    __shared__ short w1f[64 * 64 * 8];    // 64 KiB  frag-linear W1
    __shared__ short w2f[32 * 64 * 8];    // 32 KiB  frag-linear W2
    __shared__ short c1s[8][32 * 68];     // 34 KiB

    const int t = threadIdx.x;
    const int lane = t & 63;
    const int w = t >> 6;
    const int l15 = lane & 15;
    const int kg = lane >> 4;

    // ---- stage weights into fragment-linear layout ----
    {
        const float4* w1_4 = (const float4*)W_e1;
        for (int idx4 = t; idx4 < 8192; idx4 += 512) {
            int k = idx4 >> 5, j4 = idx4 & 31;
            float4 v = w1_4[idx4];
            int s = k >> 5, kgs = (k >> 3) & 3, e = k & 7;
            int fb = s * 8;
            float vz[4] = {v.x, v.y, v.z, v.w};
            #pragma unroll
            for (int z = 0; z < 4; ++z) {
                int j = j4 * 4 + z;
                int nf = j >> 4, jl = j & 15;
                w1f[((fb + nf) * 64 + kgs * 16 + jl) * 8 + e] = (short)f2bf(vz[z]);
            }
        }
        const float4* w2_4 = (const float4*)W_e2;
        for (int idx4 = t; idx4 < 4096; idx4 += 512) {
            int k = idx4 >> 5, j4 = idx4 & 31;
            float4 v = w2_4[idx4];
            int s2 = k >> 5, kgs = (k >> 3) & 3, e = k & 7;
            int fb = s2 * 8;
            float vz[4] = {v.x, v.y, v.z, v.w};
            #pragma unroll
            for (int z = 0; z < 4; ++z) {
                int j = j4 * 4 + z;
                int nf = j >> 4, jl = j & 15;
                w2f[((fb + nf) * 64 + kgs * 16 + jl) * 8 + e] = (short)f2bf(vz[z]);
            }
        }
    }
    float b1v[8], b2v[8];
    #pragma unroll
    for (int nf = 0; nf < 8; ++nf) {
        b1v[nf] = b_e1[nf * 16 + l15];
        b2v[nf] = b_e2[nf * 16 + l15];
    }
    __syncthreads();   // only block barrier

    const bf16x8* hb8 = (const bf16x8*)hbf;
    const bf16x8* w1v = (const bf16x8*)w1f;
    const bf16x8* w2v = (const bf16x8*)w2f;
    short* myc1 = &c1s[w][0];
    const int nt = N_EDGES / 32;             // 25000 tiles of 32 edges
    const int TW = gridDim.x * 8;
    const int wvid = blockIdx.x * 8 + w;
    int tile = (int)(((long long)nt * wvid) / TW);
    const int tend = (int)(((long long)nt * (wvid + 1)) / TW);
    if (tile >= tend) return;

    // current tile indices
    int el0 = elist[tile * 32 + l15];
    int el1 = elist[tile * 32 + 16 + l15];
    int ri0 = ei[el0], ci0 = ei[N_EDGES + el0];
    int ri1 = ei[el1], ci1 = ei[N_EDGES + el1];

    float rs0[8], rs1[8];
    #pragma unroll
    for (int nf = 0; nf < 8; ++nf) { rs0[nf] = 0.f; rs1[nf] = 0.f; }

    for (;;) {
        // ---- A fragments for both sub-tiles ----
        bf16x8 aA[8], aB[8];
        #pragma unroll
        for (int s = 0; s < 4; ++s) {
            aA[s]     = hb8[(size_t)ri0 * 16 + s * 4 + kg];
            aA[4 + s] = hb8[(size_t)ci0 * 16 + s * 4 + kg];
            aB[s]     = hb8[(size_t)ri1 * 16 + s * 4 + kg];
            aB[4 + s] = hb8[(size_t)ci1 * 16 + s * 4 + kg];
        }

        // ---- prefetch next tile indices ----
        const bool hn = (tile + 1 < tend);
        int el0n = 0, el1n = 0, ri0n = 0, ci0n = 0, ri1n = 0, ci1n = 0;
        if (hn) {
            el0n = elist[(tile + 1) * 32 + l15];
            el1n = elist[(tile + 1) * 32 + 16 + l15];
            ri0n = ei[el0n]; ci0n = ei[N_EDGES + el0n];
            ri1n = ei[el1n]; ci1n = ei[N_EDGES + el1n];
        }

        // ---- GEMM1: [32x256] @ [256x128], B shared by both subs ----
        f32x4 acc0[8], acc1[8];
        #pragma unroll
        for (int nf = 0; nf < 8; ++nf) {
            acc0[nf] = (f32x4){0.f, 0.f, 0.f, 0.f};
            acc1[nf] = (f32x4){0.f, 0.f, 0.f, 0.f};
        }
        #pragma unroll
        for (int s = 0; s < 8; ++s) {
            #pragma unroll
            for (int nf = 0; nf < 8; ++nf) {
                bf16x8 b = w1v[(s * 8 + nf) * 64 + lane];
                acc0[nf] = __builtin_amdgcn_mfma_f32_16x16x32_bf16(aA[s], b, acc0[nf], 0, 0, 0);
                acc1[nf] = __builtin_amdgcn_mfma_f32_16x16x32_bf16(aB[s], b, acc1[nf], 0, 0, 0);
            }
        }

        // ---- GEMM2 in two 64-col phases through stride-68 scratch ----
        f32x4 acc20[8], acc21[8];
        #pragma unroll
        for (int nf = 0; nf < 8; ++nf) {
            acc20[nf] = (f32x4){0.f, 0.f, 0.f, 0.f};
            acc21[nf] = (f32x4){0.f, 0.f, 0.f, 0.f};
        }
        #pragma unroll
        for (int half = 0; half < 2; ++half) {
            #pragma unroll
            for (int nfh = 0; nfh < 4; ++nfh) {
                int nf = half * 4 + nfh;
                #pragma unroll
                for (int r = 0; r < 4; ++r) {
                    int row = kg * 4 + r;
                    int c = nfh * 16 + l15;
                    myc1[row * 68 + c] = (short)f2bf(silu_f(acc0[nf][r] + b1v[nf]));
                    myc1[(16 + row) * 68 + c] = (short)f2bf(silu_f(acc1[nf][r] + b1v[nf]));
                }
            }
            #pragma unroll
            for (int s2l = 0; s2l < 2; ++s2l) {
                int k0h = s2l * 32 + kg * 8;
                int base0 = l15 * 68 + k0h;
                int base1 = (16 + l15) * 68 + k0h;
                bf16x4 lo0 = *(const bf16x4*)&myc1[base0];
                bf16x4 hi0 = *(const bf16x4*)&myc1[base0 + 4];
                bf16x4 lo1 = *(const bf16x4*)&myc1[base1];
                bf16x4 hi1 = *(const bf16x4*)&myc1[base1 + 4];
                bf16x8 a20, a21;
                #pragma unroll
                for (int z = 0; z < 4; ++z) {
                    a20[z] = lo0[z]; a20[4 + z] = hi0[z];
                    a21[z] = lo1[z]; a21[4 + z] = hi1[z];
                }
                int s2 = half * 2 + s2l;
                #pragma unroll
                for (int nf = 0; nf < 8; ++nf) {
                    bf16x8 b = w2v[(s2 * 8 + nf) * 64 + lane];
                    acc20[nf] = __builtin_amdgcn_mfma_f32_16x16x32_bf16(a20, b, acc20[nf], 0, 0, 0);
                    acc21[nf] = __builtin_amdgcn_mfma_f32_16x16x32_bf16(a21, b, acc21[nf], 0, 0, 0);
                }
            }
        }

        // ---- outputs: sub 0 ----
        {
            int rw_[4], ew_[4];
            #pragma unroll
            for (int r = 0; r < 4; ++r) {
                rw_[r] = __shfl(ri0, kg * 4 + r);
                ew_[r] = __shfl(el0, kg * 4 + r);
            }
            int rwn0 = hn ? __shfl(ri0n, kg * 4) : -1;
            #pragma unroll
            for (int r = 0; r < 4; ++r) {
                float* efp = ef_out + (size_t)ew_[r] * 128;
                #pragma unroll
                for (int nf = 0; nf < 8; ++nf) {
                    int col = nf * 16 + l15;
                    float v = silu_f(acc20[nf][r] + b2v[nf]);
                    __builtin_nontemporal_store(v, efp + col);
                    rs0[nf] += v;
                }
                bool end = (r < 3) ? (rw_[r + 1] != rw_[r]) : (rw_[3] != rwn0);
                if (end) {
                    short* agp = agg_bf + (size_t)rw_[r] * 128;
                    #pragma unroll
                    for (int nf = 0; nf < 8; ++nf) {
                        float vn = __shfl_xor(rs0[nf], 1);
                        if ((l15 & 1) == 0) {
                            shortx2 pk;
                            pk.x = (short)f2bf(rs0[nf]);
                            pk.y = (short)f2bf(vn);
                            atomic_pk_add_bf16(agp + nf * 16 + l15, pk);
                        }
                        rs0[nf] = 0.f;
                    }
                }
            }
        }
        // ---- outputs: sub 1 ----
        {
            int rw_[4], ew_[4];
            #pragma unroll
            for (int r = 0; r < 4; ++r) {
                rw_[r] = __shfl(ri1, kg * 4 + r);
                ew_[r] = __shfl(el1, kg * 4 + r);
            }
            int rwn0 = hn ? __shfl(ri1n, kg * 4) : -1;
            #pragma unroll
            for (int r = 0; r < 4; ++r) {
                float* efp = ef_out + (size_t)ew_[r] * 128;
                #pragma unroll
                for (int nf = 0; nf < 8; ++nf) {
                    int col = nf * 16 + l15;
                    float v = silu_f(acc21[nf][r] + b2v[nf]);
                    __builtin_nontemporal_store(v, efp + col);
                    rs1[nf] += v;
                }
                bool end = (r < 3) ? (rw_[r + 1] != rw_[r]) : (rw_[3] != rwn0);
                if (end) {
                    short* agp = agg_bf + (size_t)rw_[r] * 128;
                    #pragma unroll
                    for (int nf = 0; nf < 8; ++nf) {
                        float vn = __shfl_xor(rs1[nf], 1);
                        if ((l15 & 1) == 0) {
                            shortx2 pk;
                            pk.x = (short)f2bf(rs1[nf]);
                            pk.y = (short)f2bf(vn);
                            atomic_pk_add_bf16(agp + nf * 16 + l15, pk);
                        }
                        rs1[nf] = 0.f;
                    }
                }
            }
        }

        if (!hn) break;
        tile += 1;
        el0 = el0n; el1 = el1n;
        ri0 = ri0n; ci0 = ci0n;
        ri1 = ri1n; ci1 = ci1n;
    }
}

// ---------------------------------------------------------------------------
// Fused node kernel, 16 waves/block: q = [h_bf,agg_bf]@W_enc+b_enc;
// v = q/||q||; out = h + v@D + b_dec.  Fragment-linear weights.
// ---------------------------------------------------------------------------
__global__ __launch_bounds__(1024)
__attribute__((amdgpu_waves_per_eu(4, 4)))
void node_kernel(const short* __restrict__ hbf,
                 const short* __restrict__ agg_bf,
                 const float* __restrict__ W_enc,
                 const float* __restrict__ b_enc,
                 const short* __restrict__ Dt_bf,
                 const float* __restrict__ b_dec,
                 const float* __restrict__ h,
                 float* __restrict__ out) {
    __shared__ short wef[64 * 64 * 8];   // 64 KiB  frag-linear W_enc
    __shared__ short dtf[32 * 64 * 8];   // 32 KiB  frag-linear D^T
    __shared__ short c1s[16][16 * 68];   // 34 KiB

    const int t = threadIdx.x;
    const int lane = t & 63;
    const int w = t >> 6;
    const int l15 = lane & 15;
    const int kg = lane >> 4;

    {
        const float4* we4 = (const float4*)W_enc;
        for (int idx4 = t; idx4 < 8192; idx4 += 1024) {
            int k = idx4 >> 5, j4 = idx4 & 31;
            float4 v = we4[idx4];
            int s = k >> 5, kgs = (k >> 3) & 3, e = k & 7;
            int fb = s * 8;
            float vz[4] = {v.x, v.y, v.z, v.w};
            #pragma unroll
            for (int z = 0; z < 4; ++z) {
                int j = j4 * 4 + z;
                int nf = j >> 4, jl = j & 15;
                wef[((fb + nf) * 64 + kgs * 16 + jl) * 8 + e] = (short)f2bf(vz[z]);
            }
        }
        const bf16x8* dt8 = (const bf16x8*)Dt_bf;
        bf16x8* dtv = (bf16x8*)dtf;
        for (int idx8 = t; idx8 < 2048; idx8 += 1024) {
            int brow = idx8 >> 4, kslot = idx8 & 15;
            int s2 = kslot >> 2, kgs = kslot & 3;
            int nf = brow >> 4, jl = brow & 15;
            dtv[(s2 * 8 + nf) * 64 + kgs * 16 + jl] = dt8[idx8];
        }
    }
    float bj1[8], bj2[8];
    #pragma unroll
    for (int nf = 0; nf < 8; ++nf) {
        bj1[nf] = b_enc[nf * 16 + l15];
        bj2[nf] = b_dec[nf * 16 + l15];
    }
    __syncthreads();

    const bf16x8* hb8 = (const bf16x8*)hbf;
    const bf16x8* ab8 = (const bf16x8*)agg_bf;
    const bf16x8* wev = (const bf16x8*)wef;
    const bf16x8* dtv = (const bf16x8*)dtf;
    short* myc1 = &c1s[w][0];
    const int nt = N_NODES / 16;
    const int tile = blockIdx.x * 16 + w;
    if (tile >= nt) return;

    const int node = tile * 16 + l15;
    bf16x8 a[8];
    #pragma unroll
    for (int s = 0; s < 4; ++s) a[s] = hb8[(size_t)node * 16 + s * 4 + kg];
    #pragma unroll
    for (int s = 0; s < 4; ++s) a[4 + s] = ab8[(size_t)node * 16 + s * 4 + kg];

    f32x4 acc[8];
    #pragma unroll
    for (int nf = 0; nf < 8; ++nf) acc[nf] = (f32x4){0.f, 0.f, 0.f, 0.f};
    #pragma unroll
    for (int s = 0; s < 8; ++s) {
        #pragma unroll
        for (int nf = 0; nf < 8; ++nf) {
            bf16x8 b = wev[(s * 8 + nf) * 64 + lane];
            acc[nf] = __builtin_amdgcn_mfma_f32_16x16x32_bf16(a[s], b, acc[nf], 0, 0, 0);
        }
    }

    float nr[4] = {0.f, 0.f, 0.f, 0.f};
    #pragma unroll
    for (int nf = 0; nf < 8; ++nf) {
        #pragma unroll
        for (int r = 0; r < 4; ++r) {
            acc[nf][r] += bj1[nf];
            nr[r] += acc[nf][r] * acc[nf][r];
        }
    }
    #pragma unroll
    for (int r = 0; r < 4; ++r) {
        nr[r] += __shfl_xor(nr[r], 1);
        nr[r] += __shfl_xor(nr[r], 2);
        nr[r] += __shfl_xor(nr[r], 4);
        nr[r] += __shfl_xor(nr[r], 8);
        nr[r] = 1.0f / sqrtf(nr[r] + 1e-12f);
    }

    f32x4 acc2[8];
    #pragma unroll
    for (int nf = 0; nf < 8; ++nf) acc2[nf] = (f32x4){0.f, 0.f, 0.f, 0.f};
    #pragma unroll
    for (int half = 0; half < 2; ++half) {
        #pragma unroll
        for (int nfh = 0; nfh < 4; ++nfh) {
            int nf = half * 4 + nfh;
            #pragma unroll
            for (int r = 0; r < 4; ++r) {
                int row = kg * 4 + r;
                int c = nfh * 16 + l15;
                myc1[row * 68 + c] = (short)f2bf(acc[nf][r] * nr[r]);
            }
        }
        #pragma unroll
        for (int s2l = 0; s2l < 2; ++s2l) {
            int k0h = s2l * 32 + kg * 8;
            int base = l15 * 68 + k0h;
            bf16x4 lo = *(const bf16x4*)&myc1[base];
            bf16x4 hi = *(const bf16x4*)&myc1[base + 4];
            bf16x8 a2;
            #pragma unroll
            for (int z = 0; z < 4; ++z) { a2[z] = lo[z]; a2[4 + z] = hi[z]; }
            int s2 = half * 2 + s2l;
            #pragma unroll
            for (int nf = 0; nf < 8; ++nf) {
                bf16x8 b = dtv[(s2 * 8 + nf) * 64 + lane];
                acc2[nf] = __builtin_amdgcn_mfma_f32_16x16x32_bf16(a2, b, acc2[nf], 0, 0, 0);
            }
        }
    }

    #pragma unroll
    for (int r = 0; r < 4; ++r) {
        size_t rowb = (size_t)(tile * 16 + kg * 4 + r) * 128;
        #pragma unroll
        for (int nf = 0; nf < 8; ++nf) {
            int col = nf * 16 + l15;
            out[rowb + col] = h[rowb + col] + acc2[nf][r] + bj2[nf];
        }
    }
}

// ---------------------------------------------------------------------------
extern "C" void kernel_launch(void* const* d_in, const int* in_sizes, int n_in,
                              void* d_out, int out_size, void* d_ws, size_t ws_size,
                              hipStream_t stream) {
    const float* h      = (const float*)d_in[0];
    const int*   ei     = (const int*)d_in[1];
    const float* W_e1   = (const float*)d_in[2];
    const float* b_e1   = (const float*)d_in[3];
    const float* W_e2   = (const float*)d_in[4];
    const float* b_e2   = (const float*)d_in[5];
    const float* W_enc  = (const float*)d_in[6];
    const float* b_enc  = (const float*)d_in[7];
    const float* coeffs = (const float*)d_in[8];
    const float* A_real = (const float*)d_in[9];
    const float* A_imag = (const float*)d_in[10];
    const float* W_dec  = (const float*)d_in[11];
    const float* b_dec  = (const float*)d_in[12];

    float* out    = (float*)d_out;                 // N*128
    float* ef_out = out + (size_t)N_NODES * 128;   // E*128

    short* agg_bf = (short*)d_ws;                        // N*128 bf16
    int*   cnt    = (int*)(agg_bf + (size_t)N_NODES * 128);   // 50176 ints
    short* h_bf   = (short*)(cnt + 50176);               // N*128 bf16
    int*   cursor = (int*)(h_bf + (size_t)N_NODES * 128);
    int*   elist  = cursor + 50176;                      // N_EDGES ints
    float* small  = (float*)(elist + N_EDGES);
    float* Ybuf   = small;                 // 65536
    float* ReM    = Ybuf + 65536;          // 16384
    float* Hbuf   = ReM + 16384;           // 65536
    float* Xa     = Hbuf + 65536;          // 65536
    float* Xb     = Xa + 65536;            // 65536
    float* Tbuf   = Xb + 65536;            // 65536
    short* Dt_bf  = (short*)(Tbuf + 65536);// 16384 shorts

    // one memset covers agg_bf + cnt (adjacent)
    hipMemsetAsync(agg_bf, 0, (size_t)N_NODES * 128 * sizeof(short) + 50176 * sizeof(int),
                   stream);

    // K1: h->bf16 + count  ||  hmat
    prep_kernel<<<3133, 256, 0, stream>>>(h, h_bf, ei, cnt, A_real, A_imag, Hbuf, Xa);
    // K2: ns_t(iter1) || scan
    nst_scan_kernel<<<33, 1024, 0, stream>>>(Hbuf, Xa, Tbuf, cnt, cursor);
    // K3: fill || ns_x(iter1)
    fill_nsx_kernel<<<814, 1024, 0, stream>>>(ei, cursor, elist, Xa, Tbuf, Xb);
    // NS iteration 2
    ns_t_kernel<<<32, 1024, 0, stream>>>(Hbuf, Xb, Tbuf);
    ns_x_kernel<<<32, 1024, 0, stream>>>(Xb, Tbuf, Xa);

    gateperm_kernel<<<2, 1024, 0, stream>>>(Xa, coeffs, Ybuf);
    combine1_kernel<<<32, 512, 0, stream>>>(Ybuf, ReM);
    combine2_kernel<<<32, 512, 0, stream>>>(ReM, W_dec, Dt_bf);

    // edge MLP (32-edge tiles, CSR contiguous, carried aggregation)
    edge_kernel<<<256, 512, 0, stream>>>(h_bf, ei, elist, W_e1, b_e1, W_e2, b_e2,
                                         ef_out, agg_bf);

    // fused encode+decode
    node_kernel<<<196, 1024, 0, stream>>>(h_bf, agg_bf, W_enc, b_enc, Dt_bf, b_dec, h, out);
}

// Round 13
// 657.963 us; speedup vs baseline: 1.0436x; 1.0436x over previous
//
#include <hip/hip_runtime.h>
#include <hip/hip_cooperative_groups.h>
#include <math.h>

namespace cg = cooperative_groups;

#define N_NODES 50000
#define N_EDGES 800000

typedef __attribute__((ext_vector_type(8))) short bf16x8;
typedef __attribute__((ext_vector_type(4))) short bf16x4;
typedef __attribute__((ext_vector_type(2))) short shortx2;
typedef __attribute__((ext_vector_type(4))) float f32x4;

__device__ __forceinline__ float silu_f(float x) {
    float d = 1.0f + __expf(-x);
    return x * __builtin_amdgcn_rcpf(d);
}

__device__ __forceinline__ unsigned short f2bf(float x) {
    union { float f; unsigned u; } v; v.f = x;
    unsigned r = v.u + 0x7FFFu + ((v.u >> 16) & 1u);
    return (unsigned short)(r >> 16);
}

__device__ __forceinline__ void atomic_pk_add_bf16(short* addr, shortx2 v) {
    typedef shortx2 __attribute__((address_space(1)))* gp1;
    __builtin_amdgcn_global_atomic_fadd_v2bf16((gp1)(unsigned long long)addr, v);
}

// ---------------------------------------------------------------------------
// K1: fused h f32->bf16 + CSR degree count (blocks 0..3124) and
//     H = A + A^H, X0 = H - iI (blocks 3125..3132).
// ---------------------------------------------------------------------------
__global__ __launch_bounds__(256) void prep_kernel(const float* __restrict__ h,
                                                   short* __restrict__ hbf,
                                                   const int* __restrict__ ei,
                                                   int* __restrict__ cnt,
                                                   const float* __restrict__ A_real,
                                                   const float* __restrict__ A_imag,
                                                   float* __restrict__ H,
                                                   float* __restrict__ X) {
    const int bid = blockIdx.x;
    const int t = threadIdx.x;
    if (bid < 3125) {
        int i = bid * 256 + t;
        const float4* h4 = (const float4*)h;
        float4 v0 = h4[i * 2], v1 = h4[i * 2 + 1];
        bf16x8 b;
        b[0] = (short)f2bf(v0.x); b[1] = (short)f2bf(v0.y);
        b[2] = (short)f2bf(v0.z); b[3] = (short)f2bf(v0.w);
        b[4] = (short)f2bf(v1.x); b[5] = (short)f2bf(v1.y);
        b[6] = (short)f2bf(v1.z); b[7] = (short)f2bf(v1.w);
        ((bf16x8*)hbf)[i] = b;
        atomicAdd(&cnt[ei[i]], 1);
    } else {
        int p = bid - 3125;          // 0..7
        int L = p >> 2, q4 = p & 3;
        const float* ar = A_real + L * 16384;
        const float* ai = A_imag + L * 16384;
        float* hre = H + L * 32768;
        float* him = hre + 16384;
        float* xre = X + L * 32768;
        float* xim = xre + 16384;
        for (int m = 0; m < 16; ++m) {
            int idx = q4 * 4096 + t + 256 * m;
            int i = idx >> 7, j = idx & 127;
            float hr = ar[idx] + ar[j * 128 + i];
            float hi = ai[idx] - ai[j * 128 + i];
            hre[idx] = hr;
            him[idx] = hi;
            xre[idx] = hr;
            xim[idx] = hi - (i == j ? 1.0f : 0.0f);
        }
    }
}

// ---------------------------------------------------------------------------
// NS bodies (1024 threads, 32 blocks: 16 per layer, 8 rows each)
// ---------------------------------------------------------------------------
__device__ __forceinline__ void ns_t_body(int blk, int t,
                                          const float* __restrict__ H,
                                          const float* __restrict__ X,
                                          float* __restrict__ T) {
    const int L = blk >> 4;
    const int i = (blk & 15) * 8 + (t >> 7);
    const int j = t & 127;
    const float* hre = H + L * 32768;
    const float* him = hre + 16384;
    const float* xre = X + L * 32768;
    const float* xim = xre + 16384;
    float accr = 0.f, acci = 0.f;
    #pragma unroll 4
    for (int k = 0; k < 128; ++k) {
        float hr = hre[i * 128 + k], hi = him[i * 128 + k];
        float xr = xre[k * 128 + j], xi = xim[k * 128 + j];
        accr += hr * xr - hi * xi;
        acci += hr * xi + hi * xr;
    }
    T[L * 32768 + i * 128 + j]          = accr - xim[i * 128 + j];
    T[L * 32768 + 16384 + i * 128 + j]  = acci + xre[i * 128 + j];
}

__device__ __forceinline__ void ns_x_body(int blk, int t,
                                          const float* __restrict__ X,
                                          const float* __restrict__ T,
                                          float* __restrict__ Xout) {
    const int L = blk >> 4;
    const int i = (blk & 15) * 8 + (t >> 7);
    const int j = t & 127;
    const float* xre = X + L * 32768;
    const float* xim = xre + 16384;
    const float* tre = T + L * 32768;
    const float* tim = tre + 16384;
    float accr = 0.f, acci = 0.f;
    #pragma unroll 4
    for (int k = 0; k < 128; ++k) {
        float xr = xre[i * 128 + k], xi = xim[i * 128 + k];
        float tr = tre[k * 128 + j], ti = tim[k * 128 + j];
        accr += xr * tr - xi * ti;
        acci += xr * ti + xi * tr;
    }
    Xout[L * 32768 + i * 128 + j]          = 2.0f * xre[i * 128 + j] - accr;
    Xout[L * 32768 + 16384 + i * 128 + j]  = 2.0f * xim[i * 128 + j] - acci;
}

// ---------------------------------------------------------------------------
// K2: blocks 0..31 ns_t(iter1), block 32: CSR exclusive scan.
// ---------------------------------------------------------------------------
__global__ __launch_bounds__(1024) void nst_scan_kernel(const float* __restrict__ H,
                                                        const float* __restrict__ X,
                                                        float* __restrict__ T,
                                                        const int* __restrict__ cnt,
                                                        int* __restrict__ cursor) {
    const int bid = blockIdx.x;
    const int t = threadIdx.x;
    if (bid < 32) { ns_t_body(bid, t, H, X, T); return; }
    __shared__ int sA[1024];
    __shared__ int sB[1024];
    const int CH = 49;
    int s = 0;
    #pragma unroll 4
    for (int i = 0; i < CH; ++i) {
        int idx = t * CH + i;
        if (idx < N_NODES) s += cnt[idx];
    }
    sA[t] = s;
    __syncthreads();
    int* src = sA;
    int* dst = sB;
    for (int off = 1; off < 1024; off <<= 1) {
        int v = src[t];
        if (t >= off) v += src[t - off];
        dst[t] = v;
        __syncthreads();
        int* tmp = src; src = dst; dst = tmp;
    }
    int run = (t == 0) ? 0 : src[t - 1];
    for (int i = 0; i < CH; ++i) {
        int idx = t * CH + i;
        if (idx < N_NODES) {
            cursor[idx] = run;
            run += cnt[idx];
        }
    }
}

// ---------------------------------------------------------------------------
// K3: blocks 0..781 CSR fill, blocks 782..813 ns_x(iter1).
// ---------------------------------------------------------------------------
__global__ __launch_bounds__(1024) void fill_nsx_kernel(const int* __restrict__ ei,
                                                        int* __restrict__ cursor,
                                                        int* __restrict__ elist,
                                                        const float* __restrict__ X,
                                                        const float* __restrict__ T,
                                                        float* __restrict__ Xout) {
    const int bid = blockIdx.x;
    const int t = threadIdx.x;
    if (bid < 782) {
        int e = bid * 1024 + t;
        if (e < N_EDGES) {
            int slot = atomicAdd(&cursor[ei[e]], 1);
            elist[slot] = e;
        }
        return;
    }
    ns_x_body(bid - 782, t, X, T, Xout);
}

// ---------------------------------------------------------------------------
// K4 (cooperative, 32 blocks x 1024): ns_t(iter2) -> ns_x(iter2) ->
// gateperm -> combine1 -> combine2, grid.sync() between stages.
// ---------------------------------------------------------------------------
__global__ __launch_bounds__(1024) void dchain_kernel(const float* __restrict__ H,
                                                      const float* __restrict__ Xb,
                                                      float* __restrict__ T,
                                                      float* __restrict__ Xa,
                                                      const float* __restrict__ coeffs,
                                                      float* __restrict__ Y,
                                                      float* __restrict__ ReM,
                                                      const float* __restrict__ W_dec,
                                                      short* __restrict__ Dt) {
    cg::grid_group grid = cg::this_grid();
    __shared__ float smem[128 * 129 * 2];   // 132 KiB, aliased per stage
    const int bid = blockIdx.x;
    const int t = threadIdx.x;

    // ---- NS iter 2 ----
    ns_t_body(bid, t, H, Xb, T);
    grid.sync();
    ns_x_body(bid, t, Xb, T, Xa);
    grid.sync();

    // ---- gateperm: Q = I - 2iX; butterflies; CNOT gather (blocks 0,1) ----
    if (bid < 2) {
        float* Mre = smem;
        float* Mim = smem + 128 * 129;
        const int L = bid;
        const float* xre = Xa + L * 32768;
        const float* xim = xre + 16384;
        for (int q = 0; q < 16; ++q) {
            int idx = t + 1024 * q;
            int i = idx >> 7, j = idx & 127;
            Mre[i * 129 + j] = (i == j ? 1.0f : 0.0f) + 2.0f * xim[idx];
            Mim[i * 129 + j] = -2.0f * xre[idx];
        }
        __syncthreads();

        const float tx = coeffs[2 * L + 0] * 0.5f;
        const float ty = coeffs[2 * L + 1] * 0.5f;
        const float cx = cosf(tx), sx = sinf(tx), cy = cosf(ty), sy = sinf(ty);
        const float G00r = cx * cy, G00i = sx * sy;
        const float G01r = -cx * sy, G01i = -sx * cy;
        const float G10r = cx * sy, G10i = -sx * cy;
        const float G11r = cx * cy, G11i = -sx * sy;

        for (int st = 0; st < 7; ++st) {
            int b = 1 << st;
            #pragma unroll
            for (int p = 0; p < 8; ++p) {
                int pid = t + 1024 * p;
                int col = pid & 127, ph = pid >> 7;
                int i0 = ((ph >> st) << (st + 1)) | (ph & (b - 1));
                int i1 = i0 | b;
                float v0r = Mre[i0 * 129 + col], v0i = Mim[i0 * 129 + col];
                float v1r = Mre[i1 * 129 + col], v1i = Mim[i1 * 129 + col];
                Mre[i0 * 129 + col] = G00r * v0r - G00i * v0i + G01r * v1r - G01i * v1i;
                Mim[i0 * 129 + col] = G00r * v0i + G00i * v0r + G01r * v1i + G01i * v1r;
                Mre[i1 * 129 + col] = G10r * v0r - G10i * v0i + G11r * v1r - G11i * v1i;
                Mim[i1 * 129 + col] = G10r * v0i + G10i * v0r + G11r * v1i + G11i * v1r;
            }
            __syncthreads();
        }

        const int cs[7] = {6, 5, 4, 3, 2, 1, 0};
        const int ts[7] = {0, 6, 5, 4, 3, 2, 1};
        float* yre = Y + L * 32768;
        float* yim = yre + 16384;
        for (int q = 0; q < 16; ++q) {
            int idx = t + 1024 * q;
            int ii_ = idx >> 7, col = idx & 127;
            int s = ii_;
            #pragma unroll
            for (int m = 0; m < 7; ++m) {
                int cbit = 1 << (6 - cs[m]);
                int tbit = 1 << (6 - ts[m]);
                if (s & cbit) s ^= tbit;
            }
            yre[idx] = Mre[s * 129 + col];
            yim[idx] = Mim[s * 129 + col];
        }
    }
    grid.sync();

    // ---- combine1: ReM = Re(Y2*Y1), blocks 0..15, 8 rows each ----
    if (bid < 16) {
        float* q1r = smem;
        float* q1i = smem + 16384;
        for (int q = 0; q < 16; ++q) {
            q1r[t + 1024 * q] = Y[t + 1024 * q];
            q1i[t + 1024 * q] = Y[16384 + t + 1024 * q];
        }
        __syncthreads();
        const float* q2re = Y + 32768;
        const float* q2im = Y + 49152;
        int i = bid * 8 + (t >> 7);
        int j = t & 127;
        float acc = 0.f;
        for (int k = 0; k < 128; ++k) {
            acc += q2re[i * 128 + k] * q1r[k * 128 + j] - q2im[i * 128 + k] * q1i[k * 128 + j];
        }
        ReM[i * 128 + j] = acc;
    }
    grid.sync();

    // ---- combine2: Dt = (ReM^T * W_dec)^T bf16, blocks 0..15 ----
    if (bid < 16) {
        float* ml = smem;
        float* wl = smem + 16384;
        __syncthreads();   // ensure combine1 reads of smem done within block
        for (int q = 0; q < 16; ++q) {
            ml[t + 1024 * q] = ReM[t + 1024 * q];
            wl[t + 1024 * q] = W_dec[t + 1024 * q];
        }
        __syncthreads();
        int k = bid * 8 + (t >> 7);
        int j = t & 127;
        float acc = 0.f;
        for (int i = 0; i < 128; ++i) {
            acc += ml[i * 128 + k] * wl[i * 128 + j];
        }
        Dt[j * 128 + k] = (short)f2bf(acc);
    }
}

// ---------------------------------------------------------------------------
// Edge MLP, CSR contiguous ranges, 16 waves/block (4/EU). Frag-linear
// weights (0-conflict), stride-68 c1 scratch. a1 registers REUSED for the
// next tile's gathers (issued after GEMM1, before atomics -> vmcnt FIFO
// decoupling with zero extra registers; peak live ~113 <= 128 cap).
// ---------------------------------------------------------------------------
__global__ __launch_bounds__(1024, 4)
__attribute__((amdgpu_waves_per_eu(4, 4)))
void edge_kernel(const short* __restrict__ hbf,
                 const int* __restrict__ ei,
                 const int* __restrict__ elist,
                 const float* __restrict__ W_e1,
                 const float* __restrict__ b_e1,
                 const float* __restrict__ W_e2,
                 const float* __restrict__ b_e2,
                 float* __restrict__ ef_out,
                 short* __restrict__ agg_bf) {
    __shared__ short w1f[64 * 64 * 8];    // 64 KiB  frag-linear W1
    __shared__ short w2f[32 * 64 * 8];    // 32 KiB  frag-linear W2
    __shared__ short c1s[16][16 * 68];    // 34 KiB

    const int t = threadIdx.x;
    const int lane = t & 63;
    const int w = t >> 6;
    const int l15 = lane & 15;
    const int kg = lane >> 4;

    // ---- stage weights into fragment-linear layout ----
    {
        const float4* w1_4 = (const float4*)W_e1;
        for (int idx4 = t; idx4 < 8192; idx4 += 1024) {
            int k = idx4 >> 5, j4 = idx4 & 31;
            float4 v = w1_4[idx4];
            int s = k >> 5, kgs = (k >> 3) & 3, e = k & 7;
            int fb = s * 8;
            float vz[4] = {v.x, v.y, v.z, v.w};
            #pragma unroll
            for (int z = 0; z < 4; ++z) {
                int j = j4 * 4 + z;
                int nf = j >> 4, jl = j & 15;
                w1f[((fb + nf) * 64 + kgs * 16 + jl) * 8 + e] = (short)f2bf(vz[z]);
            }
        }
        const float4* w2_4 = (const float4*)W_e2;
        for (int idx4 = t; idx4 < 4096; idx4 += 1024) {
            int k = idx4 >> 5, j4 = idx4 & 31;
            float4 v = w2_4[idx4];
            int s2 = k >> 5, kgs = (k >> 3) & 3, e = k & 7;
            int fb = s2 * 8;
            float vz[4] = {v.x, v.y, v.z, v.w};
            #pragma unroll
            for (int z = 0; z < 4; ++z) {
                int j = j4 * 4 + z;
                int nf = j >> 4, jl = j & 15;
                w2f[((fb + nf) * 64 + kgs * 16 + jl) * 8 + e] = (short)f2bf(vz[z]);
            }
        }
    }
    float b1v[8], b2v[8];
    #pragma unroll
    for (int nf = 0; nf < 8; ++nf) {
        b1v[nf] = b_e1[nf * 16 + l15];
        b2v[nf] = b_e2[nf * 16 + l15];
    }
    __syncthreads();   // only block barrier

    const bf16x8* hb8 = (const bf16x8*)hbf;
    const bf16x8* w1v = (const bf16x8*)w1f;
    const bf16x8* w2v = (const bf16x8*)w2f;
    short* myc1 = &c1s[w][0];
    const int nt = N_EDGES / 16;
    const int TW = gridDim.x * 16;
    const int wvid = blockIdx.x * 16 + w;
    int tile = (int)(((long long)nt * wvid) / TW);
    const int tend = (int)(((long long)nt * (wvid + 1)) / TW);
    if (tile >= tend) return;

    int el = elist[tile * 16 + l15];
    int ri = ei[el];
    int ci = ei[N_EDGES + el];
    bf16x8 a1[8];
    #pragma unroll
    for (int s = 0; s < 4; ++s) a1[s] = hb8[(size_t)ri * 16 + s * 4 + kg];
    #pragma unroll
    for (int s = 0; s < 4; ++s) a1[4 + s] = hb8[(size_t)ci * 16 + s * 4 + kg];

    bool hn = (tile + 1 < tend);
    int eln = 0, rin = 0, cin = 0;
    if (hn) {
        eln = elist[(tile + 1) * 16 + l15];
        rin = ei[eln];
        cin = ei[N_EDGES + eln];
    }

    float runsum[8];
    #pragma unroll
    for (int nf = 0; nf < 8; ++nf) runsum[nf] = 0.f;

    for (;;) {
        // ---- GEMM1: [16x256] @ [256x128] (consumes a1) ----
        f32x4 acc[8];
        #pragma unroll
        for (int nf = 0; nf < 8; ++nf) acc[nf] = (f32x4){0.f, 0.f, 0.f, 0.f};
        #pragma unroll
        for (int s = 0; s < 8; ++s) {
            #pragma unroll
            for (int nf = 0; nf < 8; ++nf) {
                bf16x8 b = w1v[(s * 8 + nf) * 64 + lane];
                acc[nf] = __builtin_amdgcn_mfma_f32_16x16x32_bf16(a1[s], b, acc[nf], 0, 0, 0);
            }
        }

        // ---- reload a1 with NEXT tile's gathers (before atomics) ----
        if (hn) {
            #pragma unroll
            for (int s = 0; s < 4; ++s) a1[s] = hb8[(size_t)rin * 16 + s * 4 + kg];
            #pragma unroll
            for (int s = 0; s < 4; ++s) a1[4 + s] = hb8[(size_t)cin * 16 + s * 4 + kg];
        }
        // indices for tile+2
        bool hn2 = (tile + 2 < tend);
        int eln2 = 0, rin2 = 0, cin2 = 0;
        if (hn2) {
            eln2 = elist[(tile + 2) * 16 + l15];
            rin2 = ei[eln2];
            cin2 = ei[N_EDGES + eln2];
        }

        // ---- GEMM2 in two 64-col phases through stride-68 scratch ----
        f32x4 acc2[8];
        #pragma unroll
        for (int nf = 0; nf < 8; ++nf) acc2[nf] = (f32x4){0.f, 0.f, 0.f, 0.f};
        #pragma unroll
        for (int half = 0; half < 2; ++half) {
            #pragma unroll
            for (int nfh = 0; nfh < 4; ++nfh) {
                int nf = half * 4 + nfh;
                #pragma unroll
                for (int r = 0; r < 4; ++r) {
                    int row = kg * 4 + r;
                    int c = nfh * 16 + l15;
                    myc1[row * 68 + c] = (short)f2bf(silu_f(acc[nf][r] + b1v[nf]));
                }
            }
            #pragma unroll
            for (int s2l = 0; s2l < 2; ++s2l) {
                int k0h = s2l * 32 + kg * 8;
                int base = l15 * 68 + k0h;
                bf16x4 lo = *(const bf16x4*)&myc1[base];
                bf16x4 hi = *(const bf16x4*)&myc1[base + 4];
                bf16x8 a2;
                #pragma unroll
                for (int z = 0; z < 4; ++z) { a2[z] = lo[z]; a2[4 + z] = hi[z]; }
                int s2 = half * 2 + s2l;
                #pragma unroll
                for (int nf = 0; nf < 8; ++nf) {
                    bf16x8 b = w2v[(s2 * 8 + nf) * 64 + lane];
                    acc2[nf] = __builtin_amdgcn_mfma_f32_16x16x32_bf16(a2, b, acc2[nf], 0, 0, 0);
                }
            }
        }

        // ---- outputs: ef stores + carried run aggregation (current tile) ----
        int rw[4], ew[4];
        #pragma unroll
        for (int r = 0; r < 4; ++r) {
            rw[r] = __shfl(ri, kg * 4 + r);
            ew[r] = __shfl(el, kg * 4 + r);
        }
        int rwn0 = hn ? __shfl(rin, kg * 4) : -1;
        #pragma unroll
        for (int r = 0; r < 4; ++r) {
            float* efp = ef_out + (size_t)ew[r] * 128;
            #pragma unroll
            for (int nf = 0; nf < 8; ++nf) {
                int col = nf * 16 + l15;
                float v = silu_f(acc2[nf][r] + b2v[nf]);
                __builtin_nontemporal_store(v, efp + col);
                runsum[nf] += v;
            }
            bool end = (r < 3) ? (rw[r + 1] != rw[r]) : (rw[3] != rwn0);
            if (end) {
                short* agp = agg_bf + (size_t)rw[r] * 128;
                #pragma unroll
                for (int nf = 0; nf < 8; ++nf) {
                    float vn = __shfl_xor(runsum[nf], 1);
                    if ((l15 & 1) == 0) {
                        shortx2 pk;
                        pk.x = (short)f2bf(runsum[nf]);
                        pk.y = (short)f2bf(vn);
                        atomic_pk_add_bf16(agp + nf * 16 + l15, pk);
                    }
                    runsum[nf] = 0.f;
                }
            }
        }

        if (!hn) break;
        tile += 1;
        el = eln; ri = rin; ci = cin;
        hn = hn2; eln = eln2; rin = rin2; cin = cin2;
    }
}

// ---------------------------------------------------------------------------
// Fused node kernel, 16 waves/block: q = [h_bf,agg_bf]@W_enc+b_enc;
// v = q/||q||; out = h + v@D + b_dec.  Fragment-linear weights.
// ---------------------------------------------------------------------------
__global__ __launch_bounds__(1024)
__attribute__((amdgpu_waves_per_eu(4, 4)))
void node_kernel(const short* __restrict__ hbf,
                 const short* __restrict__ agg_bf,
                 const float* __restrict__ W_enc,
                 const float* __restrict__ b_enc,
                 const short* __restrict__ Dt_bf,
                 const float* __restrict__ b_dec,
                 const float* __restrict__ h,
                 float* __restrict__ out) {
    __shared__ short wef[64 * 64 * 8];   // 64 KiB  frag-linear W_enc
    __shared__ short dtf[32 * 64 * 8];   // 32 KiB  frag-linear D^T
    __shared__ short c1s[16][16 * 68];   // 34 KiB

    const int t = threadIdx.x;
    const int lane = t & 63;
    const int w = t >> 6;
    const int l15 = lane & 15;
    const int kg = lane >> 4;

    {
        const float4* we4 = (const float4*)W_enc;
        for (int idx4 = t; idx4 < 8192; idx4 += 1024) {
            int k = idx4 >> 5, j4 = idx4 & 31;
            float4 v = we4[idx4];
            int s = k >> 5, kgs = (k >> 3) & 3, e = k & 7;
            int fb = s * 8;
            float vz[4] = {v.x, v.y, v.z, v.w};
            #pragma unroll
            for (int z = 0; z < 4; ++z) {
                int j = j4 * 4 + z;
                int nf = j >> 4, jl = j & 15;
                wef[((fb + nf) * 64 + kgs * 16 + jl) * 8 + e] = (short)f2bf(vz[z]);
            }
        }
        const bf16x8* dt8 = (const bf16x8*)Dt_bf;
        bf16x8* dtv = (bf16x8*)dtf;
        for (int idx8 = t; idx8 < 2048; idx8 += 1024) {
            int brow = idx8 >> 4, kslot = idx8 & 15;
            int s2 = kslot >> 2, kgs = kslot & 3;
            int nf = brow >> 4, jl = brow & 15;
            dtv[(s2 * 8 + nf) * 64 + kgs * 16 + jl] = dt8[idx8];
        }
    }
    float bj1[8], bj2[8];
    #pragma unroll
    for (int nf = 0; nf < 8; ++nf) {
        bj1[nf] = b_enc[nf * 16 + l15];
        bj2[nf] = b_dec[nf * 16 + l15];
    }
    __syncthreads();

    const bf16x8* hb8 = (const bf16x8*)hbf;
    const bf16x8* ab8 = (const bf16x8*)agg_bf;
    const bf16x8* wev = (const bf16x8*)wef;
    const bf16x8* dtv = (const bf16x8*)dtf;
    short* myc1 = &c1s[w][0];
    const int nt = N_NODES / 16;
    const int tile = blockIdx.x * 16 + w;
    if (tile >= nt) return;

    const int node = tile * 16 + l15;
    bf16x8 a[8];
    #pragma unroll
    for (int s = 0; s < 4; ++s) a[s] = hb8[(size_t)node * 16 + s * 4 + kg];
    #pragma unroll
    for (int s = 0; s < 4; ++s) a[4 + s] = ab8[(size_t)node * 16 + s * 4 + kg];

    f32x4 acc[8];
    #pragma unroll
    for (int nf = 0; nf < 8; ++nf) acc[nf] = (f32x4){0.f, 0.f, 0.f, 0.f};
    #pragma unroll
    for (int s = 0; s < 8; ++s) {
        #pragma unroll
        for (int nf = 0; nf < 8; ++nf) {
            bf16x8 b = wev[(s * 8 + nf) * 64 + lane];
            acc[nf] = __builtin_amdgcn_mfma_f32_16x16x32_bf16(a[s], b, acc[nf], 0, 0, 0);
        }
    }

    float nr[4] = {0.f, 0.f, 0.f, 0.f};
    #pragma unroll
    for (int nf = 0; nf < 8; ++nf) {
        #pragma unroll
        for (int r = 0; r < 4; ++r) {
            acc[nf][r] += bj1[nf];
            nr[r] += acc[nf][r] * acc[nf][r];
        }
    }
    #pragma unroll
    for (int r = 0; r < 4; ++r) {
        nr[r] += __shfl_xor(nr[r], 1);
        nr[r] += __shfl_xor(nr[r], 2);
        nr[r] += __shfl_xor(nr[r], 4);
        nr[r] += __shfl_xor(nr[r], 8);
        nr[r] = 1.0f / sqrtf(nr[r] + 1e-12f);
    }

    f32x4 acc2[8];
    #pragma unroll
    for (int nf = 0; nf < 8; ++nf) acc2[nf] = (f32x4){0.f, 0.f, 0.f, 0.f};
    #pragma unroll
    for (int half = 0; half < 2; ++half) {
        #pragma unroll
        for (int nfh = 0; nfh < 4; ++nfh) {
            int nf = half * 4 + nfh;
            #pragma unroll
            for (int r = 0; r < 4; ++r) {
                int row = kg * 4 + r;
                int c = nfh * 16 + l15;
                myc1[row * 68 + c] = (short)f2bf(acc[nf][r] * nr[r]);
            }
        }
        #pragma unroll
        for (int s2l = 0; s2l < 2; ++s2l) {
            int k0h = s2l * 32 + kg * 8;
            int base = l15 * 68 + k0h;
            bf16x4 lo = *(const bf16x4*)&myc1[base];
            bf16x4 hi = *(const bf16x4*)&myc1[base + 4];
            bf16x8 a2;
            #pragma unroll
            for (int z = 0; z < 4; ++z) { a2[z] = lo[z]; a2[4 + z] = hi[z]; }
            int s2 = half * 2 + s2l;
            #pragma unroll
            for (int nf = 0; nf < 8; ++nf) {
                bf16x8 b = dtv[(s2 * 8 + nf) * 64 + lane];
                acc2[nf] = __builtin_amdgcn_mfma_f32_16x16x32_bf16(a2, b, acc2[nf], 0, 0, 0);
            }
        }
    }

    #pragma unroll
    for (int r = 0; r < 4; ++r) {
        size_t rowb = (size_t)(tile * 16 + kg * 4 + r) * 128;
        #pragma unroll
        for (int nf = 0; nf < 8; ++nf) {
            int col = nf * 16 + l15;
            out[rowb + col] = h[rowb + col] + acc2[nf][r] + bj2[nf];
        }
    }
}

// ---------------------------------------------------------------------------
extern "C" void kernel_launch(void* const* d_in, const int* in_sizes, int n_in,
                              void* d_out, int out_size, void* d_ws, size_t ws_size,
                              hipStream_t stream) {
    const float* h      = (const float*)d_in[0];
    const int*   ei     = (const int*)d_in[1];
    const float* W_e1   = (const float*)d_in[2];
    const float* b_e1   = (const float*)d_in[3];
    const float* W_e2   = (const float*)d_in[4];
    const float* b_e2   = (const float*)d_in[5];
    const float* W_enc  = (const float*)d_in[6];
    const float* b_enc  = (const float*)d_in[7];
    const float* coeffs = (const float*)d_in[8];
    const float* A_real = (const float*)d_in[9];
    const float* A_imag = (const float*)d_in[10];
    const float* W_dec  = (const float*)d_in[11];
    const float* b_dec  = (const float*)d_in[12];

    float* out    = (float*)d_out;                 // N*128
    float* ef_out = out + (size_t)N_NODES * 128;   // E*128

    short* agg_bf = (short*)d_ws;                        // N*128 bf16
    int*   cnt    = (int*)(agg_bf + (size_t)N_NODES * 128);   // 50176 ints
    short* h_bf   = (short*)(cnt + 50176);               // N*128 bf16
    int*   cursor = (int*)(h_bf + (size_t)N_NODES * 128);
    int*   elist  = cursor + 50176;                      // N_EDGES ints
    float* small  = (float*)(elist + N_EDGES);
    float* Ybuf   = small;                 // 65536
    float* ReM    = Ybuf + 65536;          // 16384
    float* Hbuf   = ReM + 16384;           // 65536
    float* Xa     = Hbuf + 65536;          // 65536
    float* Xb     = Xa + 65536;            // 65536
    float* Tbuf   = Xb + 65536;            // 65536
    short* Dt_bf  = (short*)(Tbuf + 65536);// 16384 shorts

    // one memset covers agg_bf + cnt (adjacent)
    hipMemsetAsync(agg_bf, 0, (size_t)N_NODES * 128 * sizeof(short) + 50176 * sizeof(int),
                   stream);

    // K1: h->bf16 + count  ||  hmat
    prep_kernel<<<3133, 256, 0, stream>>>(h, h_bf, ei, cnt, A_real, A_imag, Hbuf, Xa);
    // K2: ns_t(iter1) || scan
    nst_scan_kernel<<<33, 1024, 0, stream>>>(Hbuf, Xa, Tbuf, cnt, cursor);
    // K3: fill || ns_x(iter1)
    fill_nsx_kernel<<<814, 1024, 0, stream>>>(ei, cursor, elist, Xa, Tbuf, Xb);

    // K4: cooperative D-chain tail (ns iter2 + gateperm + combines)
    {
        const float* Hc = Hbuf;
        const float* Xbc = Xb;
        float* Tc = Tbuf;
        float* Xac = Xa;
        const float* cc = coeffs;
        float* Yc = Ybuf;
        float* Rc = ReM;
        const float* Wd = W_dec;
        short* Dtc = Dt_bf;
        void* args[] = {&Hc, &Xbc, &Tc, &Xac, &cc, &Yc, &Rc, &Wd, &Dtc};
        hipLaunchCooperativeKernel((void*)dchain_kernel, dim3(32), dim3(1024),
                                   args, 0, stream);
    }

    // edge MLP (CSR contiguous, 16 waves/block, a1-reuse pipeline)
    edge_kernel<<<256, 1024, 0, stream>>>(h_bf, ei, elist, W_e1, b_e1, W_e2, b_e2,
                                          ef_out, agg_bf);

    // fused encode+decode
    node_kernel<<<196, 1024, 0, stream>>>(h_bf, agg_bf, W_enc, b_enc, Dt_bf, b_dec, h, out);
}

// Round 14
// 592.815 us; speedup vs baseline: 1.1583x; 1.1099x over previous
//
#include <hip/hip_runtime.h>
#include <math.h>

#define N_NODES 50000
#define N_EDGES 800000

typedef __attribute__((ext_vector_type(8))) short bf16x8;
typedef __attribute__((ext_vector_type(4))) short bf16x4;
typedef __attribute__((ext_vector_type(2))) short shortx2;
typedef __attribute__((ext_vector_type(4))) float f32x4;

__device__ __forceinline__ float silu_f(float x) {
    float d = 1.0f + __expf(-x);
    return x * __builtin_amdgcn_rcpf(d);
}

__device__ __forceinline__ unsigned short f2bf(float x) {
    union { float f; unsigned u; } v; v.f = x;
    unsigned r = v.u + 0x7FFFu + ((v.u >> 16) & 1u);
    return (unsigned short)(r >> 16);
}

__device__ __forceinline__ void atomic_pk_add_bf16(short* addr, shortx2 v) {
    typedef shortx2 __attribute__((address_space(1)))* gp1;
    __builtin_amdgcn_global_atomic_fadd_v2bf16((gp1)(unsigned long long)addr, v);
}

// ---------------------------------------------------------------------------
// K1: fused h f32->bf16 + CSR degree count (blocks 0..3124) and
//     H = A + A^H, X0 = H - iI (blocks 3125..3132).
// ---------------------------------------------------------------------------
__global__ __launch_bounds__(256) void prep_kernel(const float* __restrict__ h,
                                                   short* __restrict__ hbf,
                                                   const int* __restrict__ ei,
                                                   int* __restrict__ cnt,
                                                   const float* __restrict__ A_real,
                                                   const float* __restrict__ A_imag,
                                                   float* __restrict__ H,
                                                   float* __restrict__ X) {
    const int bid = blockIdx.x;
    const int t = threadIdx.x;
    if (bid < 3125) {
        int i = bid * 256 + t;
        const float4* h4 = (const float4*)h;
        float4 v0 = h4[i * 2], v1 = h4[i * 2 + 1];
        bf16x8 b;
        b[0] = (short)f2bf(v0.x); b[1] = (short)f2bf(v0.y);
        b[2] = (short)f2bf(v0.z); b[3] = (short)f2bf(v0.w);
        b[4] = (short)f2bf(v1.x); b[5] = (short)f2bf(v1.y);
        b[6] = (short)f2bf(v1.z); b[7] = (short)f2bf(v1.w);
        ((bf16x8*)hbf)[i] = b;
        atomicAdd(&cnt[ei[i]], 1);
    } else {
        int p = bid - 3125;          // 0..7
        int L = p >> 2, q4 = p & 3;
        const float* ar = A_real + L * 16384;
        const float* ai = A_imag + L * 16384;
        float* hre = H + L * 32768;
        float* him = hre + 16384;
        float* xre = X + L * 32768;
        float* xim = xre + 16384;
        for (int m = 0; m < 16; ++m) {
            int idx = q4 * 4096 + t + 256 * m;
            int i = idx >> 7, j = idx & 127;
            float hr = ar[idx] + ar[j * 128 + i];
            float hi = ai[idx] - ai[j * 128 + i];
            hre[idx] = hr;
            him[idx] = hi;
            xre[idx] = hr;
            xim[idx] = hi - (i == j ? 1.0f : 0.0f);
        }
    }
}

// ---------------------------------------------------------------------------
// NS bodies (1024 threads, 32 blocks: 16 per layer, 8 rows each)
// ---------------------------------------------------------------------------
__device__ __forceinline__ void ns_t_body(int blk, int t,
                                          const float* __restrict__ H,
                                          const float* __restrict__ X,
                                          float* __restrict__ T) {
    const int L = blk >> 4;
    const int i = (blk & 15) * 8 + (t >> 7);
    const int j = t & 127;
    const float* hre = H + L * 32768;
    const float* him = hre + 16384;
    const float* xre = X + L * 32768;
    const float* xim = xre + 16384;
    float accr = 0.f, acci = 0.f;
    #pragma unroll 4
    for (int k = 0; k < 128; ++k) {
        float hr = hre[i * 128 + k], hi = him[i * 128 + k];
        float xr = xre[k * 128 + j], xi = xim[k * 128 + j];
        accr += hr * xr - hi * xi;
        acci += hr * xi + hi * xr;
    }
    T[L * 32768 + i * 128 + j]          = accr - xim[i * 128 + j];
    T[L * 32768 + 16384 + i * 128 + j]  = acci + xre[i * 128 + j];
}

__device__ __forceinline__ void ns_x_body(int blk, int t,
                                          const float* __restrict__ X,
                                          const float* __restrict__ T,
                                          float* __restrict__ Xout) {
    const int L = blk >> 4;
    const int i = (blk & 15) * 8 + (t >> 7);
    const int j = t & 127;
    const float* xre = X + L * 32768;
    const float* xim = xre + 16384;
    const float* tre = T + L * 32768;
    const float* tim = tre + 16384;
    float accr = 0.f, acci = 0.f;
    #pragma unroll 4
    for (int k = 0; k < 128; ++k) {
        float xr = xre[i * 128 + k], xi = xim[i * 128 + k];
        float tr = tre[k * 128 + j], ti = tim[k * 128 + j];
        accr += xr * tr - xi * ti;
        acci += xr * ti + xi * tr;
    }
    Xout[L * 32768 + i * 128 + j]          = 2.0f * xre[i * 128 + j] - accr;
    Xout[L * 32768 + 16384 + i * 128 + j]  = 2.0f * xim[i * 128 + j] - acci;
}

// ---------------------------------------------------------------------------
// K2: blocks 0..31 ns_t(iter1), block 32: CSR exclusive scan.
// ---------------------------------------------------------------------------
__global__ __launch_bounds__(1024) void nst_scan_kernel(const float* __restrict__ H,
                                                        const float* __restrict__ X,
                                                        float* __restrict__ T,
                                                        const int* __restrict__ cnt,
                                                        int* __restrict__ cursor) {
    const int bid = blockIdx.x;
    const int t = threadIdx.x;
    if (bid < 32) { ns_t_body(bid, t, H, X, T); return; }
    __shared__ int sA[1024];
    __shared__ int sB[1024];
    const int CH = 49;
    int s = 0;
    #pragma unroll 4
    for (int i = 0; i < CH; ++i) {
        int idx = t * CH + i;
        if (idx < N_NODES) s += cnt[idx];
    }
    sA[t] = s;
    __syncthreads();
    int* src = sA;
    int* dst = sB;
    for (int off = 1; off < 1024; off <<= 1) {
        int v = src[t];
        if (t >= off) v += src[t - off];
        dst[t] = v;
        __syncthreads();
        int* tmp = src; src = dst; dst = tmp;
    }
    int run = (t == 0) ? 0 : src[t - 1];
    for (int i = 0; i < CH; ++i) {
        int idx = t * CH + i;
        if (idx < N_NODES) {
            cursor[idx] = run;
            run += cnt[idx];
        }
    }
}

// ---------------------------------------------------------------------------
// K3: blocks 0..781 CSR fill, blocks 782..813 ns_x(iter1).
// ---------------------------------------------------------------------------
__global__ __launch_bounds__(1024) void fill_nsx_kernel(const int* __restrict__ ei,
                                                        int* __restrict__ cursor,
                                                        int* __restrict__ elist,
                                                        const float* __restrict__ X,
                                                        const float* __restrict__ T,
                                                        float* __restrict__ Xout) {
    const int bid = blockIdx.x;
    const int t = threadIdx.x;
    if (bid < 782) {
        int e = bid * 1024 + t;
        if (e < N_EDGES) {
            int slot = atomicAdd(&cursor[ei[e]], 1);
            elist[slot] = e;
        }
        return;
    }
    ns_x_body(bid - 782, t, X, T, Xout);
}

__global__ __launch_bounds__(1024) void ns_t_kernel(const float* __restrict__ H,
                                                    const float* __restrict__ X,
                                                    float* __restrict__ T) {
    ns_t_body(blockIdx.x, threadIdx.x, H, X, T);
}

__global__ __launch_bounds__(1024) void ns_x_kernel(const float* __restrict__ X,
                                                    const float* __restrict__ T,
                                                    float* __restrict__ Xout) {
    ns_x_body(blockIdx.x, threadIdx.x, X, T, Xout);
}

// ---------------------------------------------------------------------------
// Q = I - 2i*X ; G^{x7} butterflies on row index; CNOT row gather.
// ---------------------------------------------------------------------------
__global__ __launch_bounds__(1024) void gateperm_kernel(const float* __restrict__ X,
                                                        const float* __restrict__ coeffs,
                                                        float* __restrict__ Y) {
    __shared__ float Mre[128 * 129];
    __shared__ float Mim[128 * 129];
    const int L = blockIdx.x;
    const int t = threadIdx.x;
    const float* xre = X + L * 32768;
    const float* xim = xre + 16384;

    for (int q = 0; q < 16; ++q) {
        int idx = t + 1024 * q;
        int i = idx >> 7, j = idx & 127;
        Mre[i * 129 + j] = (i == j ? 1.0f : 0.0f) + 2.0f * xim[idx];
        Mim[i * 129 + j] = -2.0f * xre[idx];
    }
    __syncthreads();

    const float tx = coeffs[2 * L + 0] * 0.5f;
    const float ty = coeffs[2 * L + 1] * 0.5f;
    const float cx = cosf(tx), sx = sinf(tx), cy = cosf(ty), sy = sinf(ty);
    const float G00r = cx * cy, G00i = sx * sy;
    const float G01r = -cx * sy, G01i = -sx * cy;
    const float G10r = cx * sy, G10i = -sx * cy;
    const float G11r = cx * cy, G11i = -sx * sy;

    for (int st = 0; st < 7; ++st) {
        int b = 1 << st;
        #pragma unroll
        for (int p = 0; p < 8; ++p) {
            int pid = t + 1024 * p;
            int col = pid & 127, ph = pid >> 7;
            int i0 = ((ph >> st) << (st + 1)) | (ph & (b - 1));
            int i1 = i0 | b;
            float v0r = Mre[i0 * 129 + col], v0i = Mim[i0 * 129 + col];
            float v1r = Mre[i1 * 129 + col], v1i = Mim[i1 * 129 + col];
            Mre[i0 * 129 + col] = G00r * v0r - G00i * v0i + G01r * v1r - G01i * v1i;
            Mim[i0 * 129 + col] = G00r * v0i + G00i * v0r + G01r * v1i + G01i * v1r;
            Mre[i1 * 129 + col] = G10r * v0r - G10i * v0i + G11r * v1r - G11i * v1i;
            Mim[i1 * 129 + col] = G10r * v0i + G10i * v0r + G11r * v1i + G11i * v1r;
        }
        __syncthreads();
    }

    const int cs[7] = {6, 5, 4, 3, 2, 1, 0};
    const int ts[7] = {0, 6, 5, 4, 3, 2, 1};
    float* yre = Y + L * 32768;
    float* yim = yre + 16384;
    for (int q = 0; q < 16; ++q) {
        int idx = t + 1024 * q;
        int ii_ = idx >> 7, col = idx & 127;
        int s = ii_;
        #pragma unroll
        for (int m = 0; m < 7; ++m) {
            int cbit = 1 << (6 - cs[m]);
            int tbit = 1 << (6 - ts[m]);
            if (s & cbit) s ^= tbit;
        }
        yre[idx] = Mre[s * 129 + col];
        yim[idx] = Mim[s * 129 + col];
    }
}

__global__ __launch_bounds__(512) void combine1_kernel(const float* __restrict__ Y,
                                                       float* __restrict__ ReM) {
    __shared__ float q1r[16384];
    __shared__ float q1i[16384];
    const int t = threadIdx.x;
    const float* q1re = Y;
    const float* q1im = Y + 16384;
    const float* q2re = Y + 32768;
    const float* q2im = Y + 49152;
    for (int q = 0; q < 32; ++q) {
        q1r[t + 512 * q] = q1re[t + 512 * q];
        q1i[t + 512 * q] = q1im[t + 512 * q];
    }
    __syncthreads();
    int i = blockIdx.x * 4 + (t >> 7);
    int j = t & 127;
    float acc = 0.f;
    for (int k = 0; k < 128; ++k) {
        acc += q2re[i * 128 + k] * q1r[k * 128 + j] - q2im[i * 128 + k] * q1i[k * 128 + j];
    }
    ReM[i * 128 + j] = acc;
}

__global__ __launch_bounds__(512) void combine2_kernel(const float* __restrict__ ReM,
                                                       const float* __restrict__ W_dec,
                                                       short* __restrict__ Dt) {
    __shared__ float ml[16384];
    __shared__ float wl[16384];
    const int t = threadIdx.x;
    for (int q = 0; q < 32; ++q) {
        ml[t + 512 * q] = ReM[t + 512 * q];
        wl[t + 512 * q] = W_dec[t + 512 * q];
    }
    __syncthreads();
    int k = blockIdx.x * 4 + (t >> 7);
    int j = t & 127;
    float acc = 0.f;
    for (int i = 0; i < 128; ++i) {
        acc += ml[i * 128 + k] * wl[i * 128 + j];
    }
    Dt[j * 128 + k] = (short)f2bf(acc);
}

// ---------------------------------------------------------------------------
// Edge MLP, CSR contiguous ranges, 12 waves/block (3/EU) — the verified
// best operating point (R11: 308-314us, VGPR 72, no spill). Frag-linear
// weights (0-conflict), stride-68 c1 scratch, a1n prefetch between GEMMs,
// carried run aggregation. NEW: s_setprio(1) around MFMA clusters (T5 —
// waves here are phase-independent, the regime where setprio pays).
// ---------------------------------------------------------------------------
__global__ __launch_bounds__(768)
__attribute__((amdgpu_waves_per_eu(3, 3)))
void edge_kernel(const short* __restrict__ hbf,
                 const int* __restrict__ ei,
                 const int* __restrict__ elist,
                 const float* __restrict__ W_e1,
                 const float* __restrict__ b_e1,
                 const float* __restrict__ W_e2,
                 const float* __restrict__ b_e2,
                 float* __restrict__ ef_out,
                 short* __restrict__ agg_bf) {
    __shared__ short w1f[64 * 64 * 8];    // 64 KiB  frag-linear W1
    __shared__ short w2f[32 * 64 * 8];    // 32 KiB  frag-linear W2
    __shared__ short c1s[12][16 * 68];    // 25.5 KiB

    const int t = threadIdx.x;
    const int lane = t & 63;
    const int w = t >> 6;
    const int l15 = lane & 15;
    const int kg = lane >> 4;

    // ---- stage weights into fragment-linear layout (coalesced reads) ----
    {
        const float4* w1_4 = (const float4*)W_e1;
        for (int idx4 = t; idx4 < 8192; idx4 += 768) {
            int k = idx4 >> 5, j4 = idx4 & 31;
            float4 v = w1_4[idx4];
            int s = k >> 5, kgs = (k >> 3) & 3, e = k & 7;
            int fb = s * 8;
            float vz[4] = {v.x, v.y, v.z, v.w};
            #pragma unroll
            for (int z = 0; z < 4; ++z) {
                int j = j4 * 4 + z;
                int nf = j >> 4, jl = j & 15;
                w1f[((fb + nf) * 64 + kgs * 16 + jl) * 8 + e] = (short)f2bf(vz[z]);
            }
        }
        const float4* w2_4 = (const float4*)W_e2;
        for (int idx4 = t; idx4 < 4096; idx4 += 768) {
            int k = idx4 >> 5, j4 = idx4 & 31;
            float4 v = w2_4[idx4];
            int s2 = k >> 5, kgs = (k >> 3) & 3, e = k & 7;
            int fb = s2 * 8;
            float vz[4] = {v.x, v.y, v.z, v.w};
            #pragma unroll
            for (int z = 0; z < 4; ++z) {
                int j = j4 * 4 + z;
                int nf = j >> 4, jl = j & 15;
                w2f[((fb + nf) * 64 + kgs * 16 + jl) * 8 + e] = (short)f2bf(vz[z]);
            }
        }
    }
    float b1v[8], b2v[8];
    #pragma unroll
    for (int nf = 0; nf < 8; ++nf) {
        b1v[nf] = b_e1[nf * 16 + l15];
        b2v[nf] = b_e2[nf * 16 + l15];
    }
    __syncthreads();   // only block barrier

    const bf16x8* hb8 = (const bf16x8*)hbf;
    const bf16x8* w1v = (const bf16x8*)w1f;
    const bf16x8* w2v = (const bf16x8*)w2f;
    short* myc1 = &c1s[w][0];
    const int nt = N_EDGES / 16;
    const int TW = gridDim.x * 12;
    const int wvid = blockIdx.x * 12 + w;
    int tile = (int)(((long long)nt * wvid) / TW);
    const int tend = (int)(((long long)nt * (wvid + 1)) / TW);
    if (tile >= tend) return;

    int el = elist[tile * 16 + l15];
    int ri = ei[el];
    int ci = ei[N_EDGES + el];
    bf16x8 a1[8];
    #pragma unroll
    for (int s = 0; s < 4; ++s) a1[s] = hb8[(size_t)ri * 16 + s * 4 + kg];
    #pragma unroll
    for (int s = 0; s < 4; ++s) a1[4 + s] = hb8[(size_t)ci * 16 + s * 4 + kg];

    bool hn = (tile + 1 < tend);
    int eln = 0, rin = 0, cin = 0;
    if (hn) {
        eln = elist[(tile + 1) * 16 + l15];
        rin = ei[eln];
        cin = ei[N_EDGES + eln];
    }

    float runsum[8];
    #pragma unroll
    for (int nf = 0; nf < 8; ++nf) runsum[nf] = 0.f;

    for (;;) {
        // indices for tile+2
        bool hn2 = (tile + 2 < tend);
        int eln2 = 0, rin2 = 0, cin2 = 0;
        if (hn2) {
            eln2 = elist[(tile + 2) * 16 + l15];
            rin2 = ei[eln2];
            cin2 = ei[N_EDGES + eln2];
        }

        // ---- GEMM1: [16x256] @ [256x128] ----
        f32x4 acc[8];
        #pragma unroll
        for (int nf = 0; nf < 8; ++nf) acc[nf] = (f32x4){0.f, 0.f, 0.f, 0.f};
        __builtin_amdgcn_s_setprio(1);
        #pragma unroll
        for (int s = 0; s < 8; ++s) {
            #pragma unroll
            for (int nf = 0; nf < 8; ++nf) {
                bf16x8 b = w1v[(s * 8 + nf) * 64 + lane];
                acc[nf] = __builtin_amdgcn_mfma_f32_16x16x32_bf16(a1[s], b, acc[nf], 0, 0, 0);
            }
        }
        __builtin_amdgcn_s_setprio(0);

        // ---- prefetch next tile's A fragments (between the GEMMs) ----
        bf16x8 a1n[8];
        if (hn) {
            #pragma unroll
            for (int s = 0; s < 4; ++s) a1n[s] = hb8[(size_t)rin * 16 + s * 4 + kg];
            #pragma unroll
            for (int s = 0; s < 4; ++s) a1n[4 + s] = hb8[(size_t)cin * 16 + s * 4 + kg];
        }

        // ---- GEMM2 in two 64-col phases through stride-68 scratch ----
        f32x4 acc2[8];
        #pragma unroll
        for (int nf = 0; nf < 8; ++nf) acc2[nf] = (f32x4){0.f, 0.f, 0.f, 0.f};
        #pragma unroll
        for (int half = 0; half < 2; ++half) {
            #pragma unroll
            for (int nfh = 0; nfh < 4; ++nfh) {
                int nf = half * 4 + nfh;
                #pragma unroll
                for (int r = 0; r < 4; ++r) {
                    int row = kg * 4 + r;
                    int c = nfh * 16 + l15;
                    myc1[row * 68 + c] = (short)f2bf(silu_f(acc[nf][r] + b1v[nf]));
                }
            }
            #pragma unroll
            for (int s2l = 0; s2l < 2; ++s2l) {
                int k0h = s2l * 32 + kg * 8;
                int base = l15 * 68 + k0h;
                bf16x4 lo = *(const bf16x4*)&myc1[base];
                bf16x4 hi = *(const bf16x4*)&myc1[base + 4];
                bf16x8 a2;
                #pragma unroll
                for (int z = 0; z < 4; ++z) { a2[z] = lo[z]; a2[4 + z] = hi[z]; }
                int s2 = half * 2 + s2l;
                __builtin_amdgcn_s_setprio(1);
                #pragma unroll
                for (int nf = 0; nf < 8; ++nf) {
                    bf16x8 b = w2v[(s2 * 8 + nf) * 64 + lane];
                    acc2[nf] = __builtin_amdgcn_mfma_f32_16x16x32_bf16(a2, b, acc2[nf], 0, 0, 0);
                }
                __builtin_amdgcn_s_setprio(0);
            }
        }

        // ---- outputs: ef stores + carried run aggregation ----
        int rw[4], ew[4];
        #pragma unroll
        for (int r = 0; r < 4; ++r) {
            rw[r] = __shfl(ri, kg * 4 + r);
            ew[r] = __shfl(el, kg * 4 + r);
        }
        int rwn0 = hn ? __shfl(rin, kg * 4) : -1;
        #pragma unroll
        for (int r = 0; r < 4; ++r) {
            float* efp = ef_out + (size_t)ew[r] * 128;
            #pragma unroll
            for (int nf = 0; nf < 8; ++nf) {
                int col = nf * 16 + l15;
                float v = silu_f(acc2[nf][r] + b2v[nf]);
                __builtin_nontemporal_store(v, efp + col);
                runsum[nf] += v;
            }
            bool end = (r < 3) ? (rw[r + 1] != rw[r]) : (rw[3] != rwn0);
            if (end) {
                short* agp = agg_bf + (size_t)rw[r] * 128;
                #pragma unroll
                for (int nf = 0; nf < 8; ++nf) {
                    float vn = __shfl_xor(runsum[nf], 1);
                    if ((l15 & 1) == 0) {
                        shortx2 pk;
                        pk.x = (short)f2bf(runsum[nf]);
                        pk.y = (short)f2bf(vn);
                        atomic_pk_add_bf16(agp + nf * 16 + l15, pk);
                    }
                    runsum[nf] = 0.f;
                }
            }
        }

        if (!hn) break;
        tile += 1;
        el = eln; ri = rin; ci = cin;
        #pragma unroll
        for (int s = 0; s < 8; ++s) a1[s] = a1n[s];
        hn = hn2; eln = eln2; rin = rin2; cin = cin2;
    }
}

// ---------------------------------------------------------------------------
// Fused node kernel, 16 waves/block: q = [h_bf,agg_bf]@W_enc+b_enc;
// v = q/||q||; out = h + v@D + b_dec.  Fragment-linear weights.
// ---------------------------------------------------------------------------
__global__ __launch_bounds__(1024)
__attribute__((amdgpu_waves_per_eu(4, 4)))
void node_kernel(const short* __restrict__ hbf,
                 const short* __restrict__ agg_bf,
                 const float* __restrict__ W_enc,
                 const float* __restrict__ b_enc,
                 const short* __restrict__ Dt_bf,
                 const float* __restrict__ b_dec,
                 const float* __restrict__ h,
                 float* __restrict__ out) {
    __shared__ short wef[64 * 64 * 8];   // 64 KiB  frag-linear W_enc
    __shared__ short dtf[32 * 64 * 8];   // 32 KiB  frag-linear D^T
    __shared__ short c1s[16][16 * 68];   // 34 KiB

    const int t = threadIdx.x;
    const int lane = t & 63;
    const int w = t >> 6;
    const int l15 = lane & 15;
    const int kg = lane >> 4;

    {
        const float4* we4 = (const float4*)W_enc;
        for (int idx4 = t; idx4 < 8192; idx4 += 1024) {
            int k = idx4 >> 5, j4 = idx4 & 31;
            float4 v = we4[idx4];
            int s = k >> 5, kgs = (k >> 3) & 3, e = k & 7;
            int fb = s * 8;
            float vz[4] = {v.x, v.y, v.z, v.w};
            #pragma unroll
            for (int z = 0; z < 4; ++z) {
                int j = j4 * 4 + z;
                int nf = j >> 4, jl = j & 15;
                wef[((fb + nf) * 64 + kgs * 16 + jl) * 8 + e] = (short)f2bf(vz[z]);
            }
        }
        const bf16x8* dt8 = (const bf16x8*)Dt_bf;
        bf16x8* dtv = (bf16x8*)dtf;
        for (int idx8 = t; idx8 < 2048; idx8 += 1024) {
            int brow = idx8 >> 4, kslot = idx8 & 15;
            int s2 = kslot >> 2, kgs = kslot & 3;
            int nf = brow >> 4, jl = brow & 15;
            dtv[(s2 * 8 + nf) * 64 + kgs * 16 + jl] = dt8[idx8];
        }
    }
    float bj1[8], bj2[8];
    #pragma unroll
    for (int nf = 0; nf < 8; ++nf) {
        bj1[nf] = b_enc[nf * 16 + l15];
        bj2[nf] = b_dec[nf * 16 + l15];
    }
    __syncthreads();

    const bf16x8* hb8 = (const bf16x8*)hbf;
    const bf16x8* ab8 = (const bf16x8*)agg_bf;
    const bf16x8* wev = (const bf16x8*)wef;
    const bf16x8* dtv = (const bf16x8*)dtf;
    short* myc1 = &c1s[w][0];
    const int nt = N_NODES / 16;
    const int tile = blockIdx.x * 16 + w;
    if (tile >= nt) return;

    const int node = tile * 16 + l15;
    bf16x8 a[8];
    #pragma unroll
    for (int s = 0; s < 4; ++s) a[s] = hb8[(size_t)node * 16 + s * 4 + kg];
    #pragma unroll
    for (int s = 0; s < 4; ++s) a[4 + s] = ab8[(size_t)node * 16 + s * 4 + kg];

    f32x4 acc[8];
    #pragma unroll
    for (int nf = 0; nf < 8; ++nf) acc[nf] = (f32x4){0.f, 0.f, 0.f, 0.f};
    __builtin_amdgcn_s_setprio(1);
    #pragma unroll
    for (int s = 0; s < 8; ++s) {
        #pragma unroll
        for (int nf = 0; nf < 8; ++nf) {
            bf16x8 b = wev[(s * 8 + nf) * 64 + lane];
            acc[nf] = __builtin_amdgcn_mfma_f32_16x16x32_bf16(a[s], b, acc[nf], 0, 0, 0);
        }
    }
    __builtin_amdgcn_s_setprio(0);

    float nr[4] = {0.f, 0.f, 0.f, 0.f};
    #pragma unroll
    for (int nf = 0; nf < 8; ++nf) {
        #pragma unroll
        for (int r = 0; r < 4; ++r) {
            acc[nf][r] += bj1[nf];
            nr[r] += acc[nf][r] * acc[nf][r];
        }
    }
    #pragma unroll
    for (int r = 0; r < 4; ++r) {
        nr[r] += __shfl_xor(nr[r], 1);
        nr[r] += __shfl_xor(nr[r], 2);
        nr[r] += __shfl_xor(nr[r], 4);
        nr[r] += __shfl_xor(nr[r], 8);
        nr[r] = 1.0f / sqrtf(nr[r] + 1e-12f);
    }

    f32x4 acc2[8];
    #pragma unroll
    for (int nf = 0; nf < 8; ++nf) acc2[nf] = (f32x4){0.f, 0.f, 0.f, 0.f};
    #pragma unroll
    for (int half = 0; half < 2; ++half) {
        #pragma unroll
        for (int nfh = 0; nfh < 4; ++nfh) {
            int nf = half * 4 + nfh;
            #pragma unroll
            for (int r = 0; r < 4; ++r) {
                int row = kg * 4 + r;
                int c = nfh * 16 + l15;
                myc1[row * 68 + c] = (short)f2bf(acc[nf][r] * nr[r]);
            }
        }
        #pragma unroll
        for (int s2l = 0; s2l < 2; ++s2l) {
            int k0h = s2l * 32 + kg * 8;
            int base = l15 * 68 + k0h;
            bf16x4 lo = *(const bf16x4*)&myc1[base];
            bf16x4 hi = *(const bf16x4*)&myc1[base + 4];
            bf16x8 a2;
            #pragma unroll
            for (int z = 0; z < 4; ++z) { a2[z] = lo[z]; a2[4 + z] = hi[z]; }
            int s2 = half * 2 + s2l;
            __builtin_amdgcn_s_setprio(1);
            #pragma unroll
            for (int nf = 0; nf < 8; ++nf) {
                bf16x8 b = dtv[(s2 * 8 + nf) * 64 + lane];
                acc2[nf] = __builtin_amdgcn_mfma_f32_16x16x32_bf16(a2, b, acc2[nf], 0, 0, 0);
            }
            __builtin_amdgcn_s_setprio(0);
        }
    }

    #pragma unroll
    for (int r = 0; r < 4; ++r) {
        size_t rowb = (size_t)(tile * 16 + kg * 4 + r) * 128;
        #pragma unroll
        for (int nf = 0; nf < 8; ++nf) {
            int col = nf * 16 + l15;
            out[rowb + col] = h[rowb + col] + acc2[nf][r] + bj2[nf];
        }
    }
}

// ---------------------------------------------------------------------------
extern "C" void kernel_launch(void* const* d_in, const int* in_sizes, int n_in,
                              void* d_out, int out_size, void* d_ws, size_t ws_size,
                              hipStream_t stream) {
    const float* h      = (const float*)d_in[0];
    const int*   ei     = (const int*)d_in[1];
    const float* W_e1   = (const float*)d_in[2];
    const float* b_e1   = (const float*)d_in[3];
    const float* W_e2   = (const float*)d_in[4];
    const float* b_e2   = (const float*)d_in[5];
    const float* W_enc  = (const float*)d_in[6];
    const float* b_enc  = (const float*)d_in[7];
    const float* coeffs = (const float*)d_in[8];
    const float* A_real = (const float*)d_in[9];
    const float* A_imag = (const float*)d_in[10];
    const float* W_dec  = (const float*)d_in[11];
    const float* b_dec  = (const float*)d_in[12];

    float* out    = (float*)d_out;                 // N*128
    float* ef_out = out + (size_t)N_NODES * 128;   // E*128

    short* agg_bf = (short*)d_ws;                        // N*128 bf16
    int*   cnt    = (int*)(agg_bf + (size_t)N_NODES * 128);   // 50176 ints
    short* h_bf   = (short*)(cnt + 50176);               // N*128 bf16
    int*   cursor = (int*)(h_bf + (size_t)N_NODES * 128);
    int*   elist  = cursor + 50176;                      // N_EDGES ints
    float* small  = (float*)(elist + N_EDGES);
    float* Ybuf   = small;                 // 65536
    float* ReM    = Ybuf + 65536;          // 16384
    float* Hbuf   = ReM + 16384;           // 65536
    float* Xa     = Hbuf + 65536;          // 65536
    float* Xb     = Xa + 65536;            // 65536
    float* Tbuf   = Xb + 65536;            // 65536
    short* Dt_bf  = (short*)(Tbuf + 65536);// 16384 shorts

    // one memset covers agg_bf + cnt (adjacent)
    hipMemsetAsync(agg_bf, 0, (size_t)N_NODES * 128 * sizeof(short) + 50176 * sizeof(int),
                   stream);

    // K1: h->bf16 + count  ||  hmat
    prep_kernel<<<3133, 256, 0, stream>>>(h, h_bf, ei, cnt, A_real, A_imag, Hbuf, Xa);
    // K2: ns_t(iter1) || scan
    nst_scan_kernel<<<33, 1024, 0, stream>>>(Hbuf, Xa, Tbuf, cnt, cursor);
    // K3: fill || ns_x(iter1)
    fill_nsx_kernel<<<814, 1024, 0, stream>>>(ei, cursor, elist, Xa, Tbuf, Xb);
    // NS iteration 2
    ns_t_kernel<<<32, 1024, 0, stream>>>(Hbuf, Xb, Tbuf);
    ns_x_kernel<<<32, 1024, 0, stream>>>(Xb, Tbuf, Xa);

    gateperm_kernel<<<2, 1024, 0, stream>>>(Xa, coeffs, Ybuf);
    combine1_kernel<<<32, 512, 0, stream>>>(Ybuf, ReM);
    combine2_kernel<<<32, 512, 0, stream>>>(ReM, W_dec, Dt_bf);

    // edge MLP (CSR contiguous, 12 waves/block, frag-linear weights, setprio)
    edge_kernel<<<256, 768, 0, stream>>>(h_bf, ei, elist, W_e1, b_e1, W_e2, b_e2,
                                         ef_out, agg_bf);

    // fused encode+decode
    node_kernel<<<196, 1024, 0, stream>>>(h_bf, agg_bf, W_enc, b_enc, Dt_bf, b_dec, h, out);
}